// Round 6
// baseline (3185.000 us; speedup 1.0000x reference)
//
#include <hip/hip_runtime.h>
#include <stdint.h>

#define R_ 4096
#define L_ 32
#define C_ 512
#define H_ 4
#define DH_ 128

typedef __bf16 bf16x8 __attribute__((ext_vector_type(8)));
typedef float f32x4 __attribute__((ext_vector_type(4)));

// ---------- bf16 bit helpers (RNE) ----------
__device__ __forceinline__ float b2f(unsigned int u) {
    union { unsigned int i; float f; } x; x.i = u << 16; return x.f;
}
__device__ __forceinline__ unsigned short f2b(float f) {
    union { float f; unsigned int i; } x; x.f = f;
    unsigned int i = x.i;
    i += 0x7fffu + ((i >> 16) & 1u);
    return (unsigned short)(i >> 16);
}
__device__ __forceinline__ void unpack8(uint4 v, float* x) {
    x[0] = b2f(v.x & 0xffffu); x[1] = b2f(v.x >> 16);
    x[2] = b2f(v.y & 0xffffu); x[3] = b2f(v.y >> 16);
    x[4] = b2f(v.z & 0xffffu); x[5] = b2f(v.z >> 16);
    x[6] = b2f(v.w & 0xffffu); x[7] = b2f(v.w >> 16);
}
__device__ __forceinline__ uint4 pack8(const float* x) {
    uint4 v;
    v.x = (unsigned)f2b(x[0]) | ((unsigned)f2b(x[1]) << 16);
    v.y = (unsigned)f2b(x[2]) | ((unsigned)f2b(x[3]) << 16);
    v.z = (unsigned)f2b(x[4]) | ((unsigned)f2b(x[5]) << 16);
    v.w = (unsigned)f2b(x[6]) | ((unsigned)f2b(x[7]) << 16);
    return v;
}

__device__ __forceinline__ void gload_lds16(const unsigned short* g, unsigned short* l) {
    __builtin_amdgcn_global_load_lds(
        (const __attribute__((address_space(1))) void*)g,
        (__attribute__((address_space(3))) void*)l, 16, 0, 0);
}

// ---------- dtype detection: 1 = bf16, 0 = fp32 ----------
__global__ __launch_bounds__(256)
void detect_kernel(const unsigned short* __restrict__ gene, int* __restrict__ flag) {
    __shared__ int cnt;
    if (threadIdx.x == 0) cnt = 0;
    __syncthreads();
    int local = 0;
    for (int j = 0; j < 8; ++j) {
        int i = threadIdx.x * 8 + j;
        unsigned short u = gene[2 * i];
        int e = (u >> 7) & 0xFF;
        if (e >= 100 && e <= 140) ++local;
    }
    atomicAdd(&cnt, local);
    __syncthreads();
    if (threadIdx.x == 0) *flag = (cnt >= 1024) ? 1 : 0;
}

// ---------- batched weight conversion/pack: one dispatch for all params ----------
#define NJOBS 32
struct CvtJobs {
    const void* src[NJOBS];
    int srcOff[NJOBS];   // element offset in source dtype
    int dstOff[NJOBS];   // u16 element offset into weight region
    int n[NJOBS];        // element count (multiple of 8)
    int cnt;
};
__global__ __launch_bounds__(256)
void cvt_jobs_kernel(CvtJobs J, unsigned short* __restrict__ base, const int* __restrict__ flag) {
    int j = blockIdx.y;
    if (j >= J.cnt) return;
    int i0 = (blockIdx.x * 256 + threadIdx.x) * 8;
    if (i0 >= J.n[j]) return;
    unsigned short* dst = base + J.dstOff[j] + i0;
    if (*flag) {
        const unsigned short* s = (const unsigned short*)J.src[j] + J.srcOff[j] + i0;
        *(uint4*)dst = *(const uint4*)s;
    } else {
        const float* s = (const float*)J.src[j] + J.srcOff[j] + i0;
        float4 a = *(const float4*)s;
        float4 b = *(const float4*)(s + 4);
        float x[8] = {a.x, a.y, a.z, a.w, b.x, b.y, b.z, b.w};
        *(uint4*)dst = pack8(x);
    }
}

// ---------- diagnostic ----------
__global__ __launch_bounds__(256)
void diag_kernel(unsigned short* __restrict__ out, int n, float val) {
    int i = blockIdx.x * 256 + threadIdx.x;
    if (i < n) out[i] = f2b(val);
}

// ---------- gather genes -> X [Mc, C] bf16, masked rows = 0 ----------
__global__ __launch_bounds__(256)
void gather_kernel(const void* __restrict__ gene_v, const int* __restrict__ gidx,
                   const int* __restrict__ lens, unsigned short* __restrict__ X,
                   const int* __restrict__ flag) {
    int tid = blockIdx.x * 256 + threadIdx.x;
    int m = tid >> 6;
    int ch = tid & 63;
    uint4 v = make_uint4(0u, 0u, 0u, 0u);
    if ((m & 31) < lens[m >> 5]) {
        size_t base = (size_t)gidx[m] * C_ + ch * 8;
        if (*flag) {
            v = *(const uint4*)((const unsigned short*)gene_v + base);
        } else {
            const float* f = (const float*)gene_v;
            float4 a = *(const float4*)(f + base);
            float4 b = *(const float4*)(f + base + 4);
            float x[8] = {a.x, a.y, a.z, a.w, b.x, b.y, b.z, b.w};
            v = pack8(x);
        }
    }
    *(uint4*)(X + (size_t)m * C_ + ch * 8) = v;
}

// ---------- seed broadcast -> S0 [Rc, C] ----------
__global__ __launch_bounds__(256)
void seed_kernel(const unsigned short* __restrict__ seed, unsigned short* __restrict__ Xs) {
    int i = blockIdx.x * 256 + threadIdx.x;
    int ch = i & 63;
    uint4 v = *(const uint4*)(seed + ch * 8);
    *(uint4*)(Xs + (size_t)i * 8) = v;
}

// ---------- final: S0 bf16 -> out (bf16|fp32 per flag) ----------
__global__ __launch_bounds__(256)
void final_kernel(const unsigned short* __restrict__ S, const int* __restrict__ lens,
                  void* __restrict__ out, const int* __restrict__ flag, size_t elem_off) {
    int i = blockIdx.x * 256 + threadIdx.x;
    int r = i >> 6;
    uint4 v = make_uint4(0u, 0u, 0u, 0u);
    if (lens[r] > 0) v = *(const uint4*)(S + (size_t)i * 8);
    if (*flag) {
        *(uint4*)((unsigned short*)out + elem_off + (size_t)i * 8) = v;
    } else {
        float x[8];
        unpack8(v, x);
        float* o = (float*)out + elem_off + (size_t)i * 8;
        *(float4*)o       = make_float4(x[0], x[1], x[2], x[3]);
        *(float4*)(o + 4) = make_float4(x[4], x[5], x[6], x[7]);
    }
}

// ---------- plain GEMM: Out[M,N] = A[M,512] @ W[N,512]^T + bias, opt ReLU ----------
// 128x256 tile, BK=32, 4 waves, global_load_lds 16B staging.
__global__ __launch_bounds__(256, 2)
void gemm_bt_kernel(const unsigned short* __restrict__ A, int lda,
                    const unsigned short* __restrict__ W,
                    const unsigned short* __restrict__ bias,
                    unsigned short* __restrict__ Out, int ldout, int relu) {
    __shared__ unsigned short As[128 * 32];
    __shared__ unsigned short Bs[256 * 32];

    const int t = threadIdx.x;
    const int wave = t >> 6, lane = t & 63;
    const int quad = lane >> 4, lr = lane & 15;
    const int wr = wave >> 1, wc = wave & 1;
    const int m0 = blockIdx.x * 128, n0 = blockIdx.y * 256;

    const int srow = wave * 16 + (lane >> 2);
    const int scol = (lane & 3) * 8;
    const unsigned short* ga0 = A + (size_t)(m0 + srow) * lda + scol;
    const unsigned short* ga1 = A + (size_t)(m0 + srow + 64) * lda + scol;
    const unsigned short* gb0 = W + (size_t)(n0 + srow) * C_ + scol;
    const unsigned short* gb1 = W + (size_t)(n0 + srow + 64) * C_ + scol;
    const unsigned short* gb2 = W + (size_t)(n0 + srow + 128) * C_ + scol;
    const unsigned short* gb3 = W + (size_t)(n0 + srow + 192) * C_ + scol;
    unsigned short* lA0 = As + wave * 512;
    unsigned short* lA1 = As + (wave + 4) * 512;
    unsigned short* lB0 = Bs + wave * 512;
    unsigned short* lB1 = Bs + (wave + 4) * 512;
    unsigned short* lB2 = Bs + (wave + 8) * 512;
    unsigned short* lB3 = Bs + (wave + 12) * 512;

    f32x4 acc[4][8] = {};

    for (int k0 = 0; k0 < C_; k0 += 32) {
        __syncthreads();
        gload_lds16(ga0 + k0, lA0);
        gload_lds16(ga1 + k0, lA1);
        gload_lds16(gb0 + k0, lB0);
        gload_lds16(gb1 + k0, lB1);
        gload_lds16(gb2 + k0, lB2);
        gload_lds16(gb3 + k0, lB3);
        __syncthreads();

        bf16x8 af[4], bfr[8];
#pragma unroll
        for (int i = 0; i < 4; ++i)
            af[i] = *(const bf16x8*)&As[(64 * wr + 16 * i + lr) * 32 + quad * 8];
#pragma unroll
        for (int j = 0; j < 8; ++j)
            bfr[j] = *(const bf16x8*)&Bs[(128 * wc + 16 * j + lr) * 32 + quad * 8];
#pragma unroll
        for (int i = 0; i < 4; ++i)
#pragma unroll
            for (int j = 0; j < 8; ++j)
                acc[i][j] = __builtin_amdgcn_mfma_f32_16x16x32_bf16(af[i], bfr[j], acc[i][j], 0, 0, 0);
    }

#pragma unroll
    for (int i = 0; i < 4; ++i) {
        int row = m0 + 64 * wr + 16 * i + quad * 4;
#pragma unroll
        for (int j = 0; j < 8; ++j) {
            int col = n0 + 128 * wc + 16 * j + lr;
            float bv = b2f(bias[col]);
#pragma unroll
            for (int r = 0; r < 4; ++r) {
                float v = acc[i][j][r] + bv;
                if (relu) v = fmaxf(v, 0.f);
                Out[(size_t)(row + r) * ldout + col] = f2b(v);
            }
        }
    }
}

// ---------- fused GEMM + (mask) + residual + LayerNorm ----------
// Out[M,512] = LN( maybe_zero(A@W^T + b) + Res ) * gamma + beta
// tile 128x512 (full N -> row stats block-local), 512 thr = 8 waves (2x4).
__global__ __launch_bounds__(512)
void gemm_ln_kernel(const unsigned short* __restrict__ A, int lda,
                    const unsigned short* __restrict__ W,
                    const unsigned short* __restrict__ bias,
                    const unsigned short* __restrict__ Res, int ldres,
                    const unsigned short* __restrict__ gamma,
                    const unsigned short* __restrict__ beta,
                    unsigned short* __restrict__ Out, int ldout,
                    const int* __restrict__ lens, int use_mask, int relu) {
    __shared__ unsigned short As[128 * 32];
    __shared__ unsigned short Bs[512 * 32];
    __shared__ float red[128][8];  // [row][wc*2 + {s,ss}]

    const int t = threadIdx.x;
    const int wave = t >> 6, lane = t & 63;
    const int quad = lane >> 4, lr = lane & 15;
    const int wr = wave >> 2, wc = wave & 3;
    const int m0 = blockIdx.x * 128;

    const int srow = (lane >> 2);
    const int scol = (lane & 3) * 8;
    const unsigned short* gA = A + (size_t)(m0 + wave * 16 + srow) * lda + scol;
    const unsigned short* gB0 = W + (size_t)((wave)      * 16 + srow) * C_ + scol;
    const unsigned short* gB1 = W + (size_t)((wave + 8)  * 16 + srow) * C_ + scol;
    const unsigned short* gB2 = W + (size_t)((wave + 16) * 16 + srow) * C_ + scol;
    const unsigned short* gB3 = W + (size_t)((wave + 24) * 16 + srow) * C_ + scol;
    unsigned short* lA  = As + wave * 512;
    unsigned short* lB0 = Bs + wave * 512;
    unsigned short* lB1 = Bs + (wave + 8) * 512;
    unsigned short* lB2 = Bs + (wave + 16) * 512;
    unsigned short* lB3 = Bs + (wave + 24) * 512;

    f32x4 acc[4][8] = {};

    for (int k0 = 0; k0 < C_; k0 += 32) {
        __syncthreads();
        gload_lds16(gA + k0, lA);
        gload_lds16(gB0 + k0, lB0);
        gload_lds16(gB1 + k0, lB1);
        gload_lds16(gB2 + k0, lB2);
        gload_lds16(gB3 + k0, lB3);
        __syncthreads();

        bf16x8 af[4], bfr[8];
#pragma unroll
        for (int i = 0; i < 4; ++i)
            af[i] = *(const bf16x8*)&As[(64 * wr + 16 * i + lr) * 32 + quad * 8];
#pragma unroll
        for (int j = 0; j < 8; ++j)
            bfr[j] = *(const bf16x8*)&Bs[(128 * wc + 16 * j + lr) * 32 + quad * 8];
#pragma unroll
        for (int i = 0; i < 4; ++i)
#pragma unroll
            for (int j = 0; j < 8; ++j)
                acc[i][j] = __builtin_amdgcn_mfma_f32_16x16x32_bf16(af[i], bfr[j], acc[i][j], 0, 0, 0);
    }

    // epilogue: bias/relu/mask, + residual, stats
    float bv[8], gv[8], btv[8];
#pragma unroll
    for (int j = 0; j < 8; ++j) {
        int col = 128 * wc + 16 * j + lr;
        bv[j] = b2f(bias[col]); gv[j] = b2f(gamma[col]); btv[j] = b2f(beta[col]);
    }
    float s[4][4] = {}, ss[4][4] = {};
#pragma unroll
    for (int i = 0; i < 4; ++i) {
#pragma unroll
        for (int r = 0; r < 4; ++r) {
            int row = m0 + 64 * wr + 16 * i + quad * 4 + r;
            bool masked = use_mask && ((row & 31) >= lens[row >> 5]);
#pragma unroll
            for (int j = 0; j < 8; ++j) {
                int col = 128 * wc + 16 * j + lr;
                float v = acc[i][j][r] + bv[j];
                if (relu) v = fmaxf(v, 0.f);
                if (masked) v = 0.f;
                v += b2f(Res[(size_t)row * ldres + col]);
                acc[i][j][r] = v;
                s[i][r] += v; ss[i][r] += v * v;
            }
        }
    }
#pragma unroll
    for (int i = 0; i < 4; ++i)
#pragma unroll
        for (int r = 0; r < 4; ++r) {
#pragma unroll
            for (int m = 1; m < 16; m <<= 1) {
                s[i][r]  += __shfl_xor(s[i][r], m);
                ss[i][r] += __shfl_xor(ss[i][r], m);
            }
        }
    if (lr == 0) {
#pragma unroll
        for (int i = 0; i < 4; ++i)
#pragma unroll
            for (int r = 0; r < 4; ++r) {
                int rl = 64 * wr + 16 * i + quad * 4 + r;
                red[rl][wc * 2] = s[i][r];
                red[rl][wc * 2 + 1] = ss[i][r];
            }
    }
    __syncthreads();
#pragma unroll
    for (int i = 0; i < 4; ++i) {
#pragma unroll
        for (int r = 0; r < 4; ++r) {
            int rl = 64 * wr + 16 * i + quad * 4 + r;
            float S = red[rl][0] + red[rl][2] + red[rl][4] + red[rl][6];
            float SS = red[rl][1] + red[rl][3] + red[rl][5] + red[rl][7];
            float mu = S * (1.f / 512.f);
            float rinv = rsqrtf(fmaxf(SS * (1.f / 512.f) - mu * mu, 0.f) + 1e-5f);
            int row = m0 + rl;
#pragma unroll
            for (int j = 0; j < 8; ++j) {
                int col = 128 * wc + 16 * j + lr;
                float y = (acc[i][j][r] - mu) * rinv * gv[j] + btv[j];
                Out[(size_t)row * ldout + col] = f2b(y);
            }
        }
    }
}

// ---------- encoder attention via MFMA: block = reaction, wave = head ----------
// QKV packed [Mc,1536]: Q cols 0..511, K 512..1023, V 1024..1535 (head h: +h*128).
// Computes S^T = K@Q^T (mask+softmax in-register), P via LDS, O = P@V.
// Writes O into the Q-slot (disjoint per (r,h) -> safe).
__global__ __launch_bounds__(256)
void attn_enc_kernel(unsigned short* __restrict__ QKV, const int* __restrict__ lens) {
    const int r = blockIdx.x;
    const int t = threadIdx.x;
    const int h = t >> 6;
    const int lane = t & 63;
    const int quad = lane >> 4, lr = lane & 15;
    const int len = lens[r];
    __shared__ unsigned short Vs[4 * 32 * 132];
    __shared__ unsigned short Ps[4 * 32 * 34];
    unsigned short* vsh = Vs + h * (32 * 132);
    unsigned short* psh = Ps + h * (32 * 34);
    unsigned short* base = QKV + (size_t)r * 32 * 1536;

    // stage V head-slice into LDS (stride 132 u16: 2-way bank max on frag reads)
    {
        int row = lane >> 1, cp = (lane & 1) * 64;
        const unsigned short* vg = base + (size_t)row * 1536 + 1024 + h * 128 + cp;
        unsigned short* vd = vsh + row * 132 + cp;
#pragma unroll
        for (int n = 0; n < 16; ++n)
            *(uint2*)(vd + n * 4) = *(const uint2*)(vg + n * 4);
    }

    // S^T = K @ Q^T  (A-frag from K rows=keys, B-frag from Q rows=queries)
    const unsigned short* Kg = base + 512 + h * 128;
    const unsigned short* Qg = base + h * 128;
    f32x4 sa[2][2] = {};
    for (int k0 = 0; k0 < 128; k0 += 32) {
        bf16x8 af[2], bfq[2];
#pragma unroll
        for (int kt = 0; kt < 2; ++kt)
            af[kt] = *(const bf16x8*)(Kg + (size_t)(kt * 16 + lr) * 1536 + k0 + quad * 8);
#pragma unroll
        for (int qt = 0; qt < 2; ++qt)
            bfq[qt] = *(const bf16x8*)(Qg + (size_t)(qt * 16 + lr) * 1536 + k0 + quad * 8);
#pragma unroll
        for (int kt = 0; kt < 2; ++kt)
#pragma unroll
            for (int qt = 0; qt < 2; ++qt)
                sa[kt][qt] = __builtin_amdgcn_mfma_f32_16x16x32_bf16(af[kt], bfq[qt], sa[kt][qt], 0, 0, 0);
    }
    __syncthreads();   // V staging visible (also covers Ps region reuse)

    // softmax over keys; lane holds key = kt*16+quad*4+reg for query q = qt*16+lr
    const float scale = 0.08838834764831845f;
    float p[2][2][4];
#pragma unroll
    for (int qt = 0; qt < 2; ++qt) {
        float mx = -3e38f;
#pragma unroll
        for (int kt = 0; kt < 2; ++kt)
#pragma unroll
            for (int reg = 0; reg < 4; ++reg) {
                int key = kt * 16 + quad * 4 + reg;
                float v = sa[kt][qt][reg] * scale;
                if (key >= len) v = -1e30f;
                p[kt][qt][reg] = v;
                mx = fmaxf(mx, v);
            }
        mx = fmaxf(mx, __shfl_xor(mx, 16));
        mx = fmaxf(mx, __shfl_xor(mx, 32));
        float sum = 0.f;
#pragma unroll
        for (int kt = 0; kt < 2; ++kt)
#pragma unroll
            for (int reg = 0; reg < 4; ++reg) {
                float e = __expf(p[kt][qt][reg] - mx);
                p[kt][qt][reg] = e;
                sum += e;
            }
        sum += __shfl_xor(sum, 16);
        sum += __shfl_xor(sum, 32);
        float inv = 1.f / sum;
#pragma unroll
        for (int kt = 0; kt < 2; ++kt)
#pragma unroll
            for (int reg = 0; reg < 4; ++reg)
                psh[(kt * 16 + quad * 4 + reg) * 34 + qt * 16 + lr] = f2b(p[kt][qt][reg] * inv);
    }
    __syncthreads();   // P visible

    // O = P @ V : A-frag P[q][key], B-frag V[key][d]; one MFMA covers all 32 keys
    union { unsigned short u[8]; bf16x8 v; } pa[2];
#pragma unroll
    for (int qt = 0; qt < 2; ++qt)
#pragma unroll
        for (int j = 0; j < 8; ++j)
            pa[qt].u[j] = psh[(quad * 8 + j) * 34 + qt * 16 + lr];

#pragma unroll
    for (int dt = 0; dt < 8; ++dt) {
        union { unsigned short u[8]; bf16x8 v; } vb;
#pragma unroll
        for (int j = 0; j < 8; ++j)
            vb.u[j] = vsh[(quad * 8 + j) * 132 + dt * 16 + lr];
#pragma unroll
        for (int qt = 0; qt < 2; ++qt) {
            f32x4 o = __builtin_amdgcn_mfma_f32_16x16x32_bf16(pa[qt].v, vb.v, (f32x4){0.f, 0.f, 0.f, 0.f}, 0, 0, 0);
#pragma unroll
            for (int reg = 0; reg < 4; ++reg) {
                int q = qt * 16 + quad * 4 + reg;
                base[(size_t)q * 1536 + h * 128 + dt * 16 + lr] = f2b(o[reg]);
            }
        }
    }
}

// ---------- PMA attention: per (r,h), 1 seed query, 32 keys; KV packed [Mc,1024] ----------
__global__ __launch_bounds__(64)
void attn_pma_kernel(const unsigned short* __restrict__ Qs_, const unsigned short* __restrict__ KV,
                     unsigned short* __restrict__ O, const int* __restrict__ lens) {
    const int r = blockIdx.x, h = blockIdx.y, t = threadIdx.x;
    __shared__ float qv[128];
    __shared__ float attn[32];
    const int len = lens[r];
    const size_t qb = (size_t)r * C_ + h * DH_;
    qv[t]      = b2f(Qs_[qb + t]);
    qv[t + 64] = b2f(Qs_[qb + t + 64]);
    __syncthreads();
    if (t < 32) {
        const unsigned short* krow = KV + ((size_t)(r * 32 + t)) * 1024 + h * DH_;
        float s = 0.f;
        for (int d = 0; d < 128; ++d) s += qv[d] * b2f(krow[d]);
        attn[t] = (t < len) ? s * 0.08838834764831845f : -1e30f;
    }
    __syncthreads();
    if (t == 0) {
        float mx = -3e38f;
        for (int k = 0; k < 32; ++k) mx = fmaxf(mx, attn[k]);
        float sum = 0.f;
        for (int k = 0; k < 32; ++k) { float e = __expf(attn[k] - mx); attn[k] = e; sum += e; }
        float inv = 1.f / sum;
        for (int k = 0; k < 32; ++k) attn[k] *= inv;
    }
    __syncthreads();
    float a0 = 0.f, a1 = 0.f;
    for (int k = 0; k < 32; ++k) {
        const unsigned short* vrow = KV + ((size_t)(r * 32 + k)) * 1024 + 512 + h * DH_;
        float a = attn[k];
        a0 += a * b2f(vrow[t]);
        a1 += a * b2f(vrow[t + 64]);
    }
    O[qb + t]      = f2b(a0);
    O[qb + t + 64] = f2b(a1);
}

extern "C" void kernel_launch(void* const* d_in, const int* in_sizes, int n_in,
                              void* d_out, int out_size, void* d_ws, size_t ws_size,
                              hipStream_t stream) {
    (void)in_sizes; (void)n_in;
    const void* gene = d_in[0];
    const int*  gidx = (const int*)d_in[1];
    const int*  lens = (const int*)d_in[2];

    int* flag = (int*)d_ws;
    unsigned short* ws0 = (unsigned short*)d_ws + 64;

    size_t off = 0;
    auto take = [&](size_t elems) { unsigned short* p = ws0 + off; off += elems; return p; };
    const size_t CC = (size_t)C_ * C_;
    unsigned short* wQKV = take(2 * 1536 * 512);   // enc blocks 0,1 packed [1536,512]
    unsigned short* wKV2 = take(1024 * 512);       // PMA K,V packed
    unsigned short* wQ2  = take(CC);
    unsigned short* wO   = take(4 * CC);
    unsigned short* wF   = take(4 * CC);
    unsigned short* wV3  = take(CC);
    unsigned short* wP   = take(CC);
    unsigned short* cbqkv = take(2 * 1536);
    unsigned short* cbkv2 = take(1024);
    unsigned short* cbq  = take(4 * C_);
    unsigned short* cbv  = take(4 * C_);
    unsigned short* cbo  = take(4 * C_);
    unsigned short* cff  = take(4 * C_);
    unsigned short* cg1  = take(4 * C_);
    unsigned short* cb1  = take(4 * C_);
    unsigned short* cg2  = take(4 * C_);
    unsigned short* cb2  = take(4 * C_);
    unsigned short* cpb  = take(C_);
    unsigned short* csd  = take(C_);
    const size_t wbytes = 128 + off * 2;

    int Rc = 0;
    const int cands[6] = {4096, 2048, 1024, 512, 256, 128};
    for (int i = 0; i < 6; ++i) {
        size_t need = wbytes + (size_t)cands[i] * 135168;
        if (need <= ws_size) { Rc = cands[i]; break; }
    }
    if (Rc == 0) {
        diag_kernel<<<(out_size + 255) / 256, 256, 0, stream>>>(
            (unsigned short*)d_out, out_size, 1000.0f + (float)(ws_size >> 20));
        return;
    }
    const int Mc = Rc * 32;

    unsigned short* Xa  = take((size_t)Mc * 512);
    unsigned short* QKV = take((size_t)Mc * 1536);
    unsigned short* Y   = QKV;                       // pma_lin out ([Mc,512], QKV dead)
    unsigned short* KVb = QKV + (size_t)Mc * 512;    // PMA K/V packed [Mc,1024]
    unsigned short* S0 = take((size_t)Rc * C_);
    unsigned short* S1 = take((size_t)Rc * C_);
    unsigned short* S2 = take((size_t)Rc * C_);

    detect_kernel<<<1, 256, 0, stream>>>((const unsigned short*)gene, flag);

    // ---- weight conversion job table (one dispatch) ----
    CvtJobs J = {};
    int nj = 0;
    auto job = [&](const void* src, int soff, unsigned short* dst, int n) {
        J.src[nj] = src; J.srcOff[nj] = soff;
        J.dstOff[nj] = (int)(dst - ws0); J.n[nj] = n; ++nj;
    };
    const int iCC = (int)CC;
    // Wq
    job(d_in[3], 0,       wQKV,                 iCC);
    job(d_in[3], iCC,     wQKV + 1536 * 512,    iCC);
    job(d_in[3], 2 * iCC, wQ2,                  iCC);
    // Wk
    job(d_in[4], 0,       wQKV + CC,                iCC);
    job(d_in[4], iCC,     wQKV + 1536 * 512 + CC,   iCC);
    job(d_in[4], 2 * iCC, wKV2,                     iCC);
    // Wv
    job(d_in[5], 0,       wQKV + 2 * CC,               iCC);
    job(d_in[5], iCC,     wQKV + 1536 * 512 + 2 * CC,  iCC);
    job(d_in[5], 2 * iCC, wKV2 + CC,                   iCC);
    job(d_in[5], 3 * iCC, wV3,                         iCC);
    // whole arrays
    job(d_in[6],  0, wO, 4 * iCC);
    job(d_in[7],  0, wF, 4 * iCC);
    job(d_in[17], 0, wP, iCC);
    // biases packed
    job(d_in[8], 0,       cbqkv,            C_);   // bq0
    job(d_in[8], C_,      cbqkv + 1536,     C_);   // bq1
    job(d_in[9], 0,       cbqkv + 512,      C_);   // bk0
    job(d_in[9], C_,      cbqkv + 1536 + 512, C_); // bk1
    job(d_in[10], 0,      cbqkv + 1024,     C_);   // bv0
    job(d_in[10], C_,     cbqkv + 1536 + 1024, C_);// bv1
    job(d_in[9], 2 * C_,  cbkv2,            C_);   // bk2
    job(d_in[10], 2 * C_, cbkv2 + 512,      C_);   // bv2
    // whole bias/ln params
    job(d_in[8],  0, cbq, 4 * C_);
    job(d_in[10], 0, cbv, 4 * C_);
    job(d_in[11], 0, cbo, 4 * C_);
    job(d_in[12], 0, cff, 4 * C_);
    job(d_in[13], 0, cg1, 4 * C_);
    job(d_in[14], 0, cb1, 4 * C_);
    job(d_in[15], 0, cg2, 4 * C_);
    job(d_in[16], 0, cb2, 4 * C_);
    job(d_in[18], 0, cpb, C_);
    job(d_in[19], 0, csd, C_);
    J.cnt = nj;
    cvt_jobs_kernel<<<dim3(512, nj), 256, 0, stream>>>(J, ws0, flag);

    for (int c = 0; c < R_ / Rc; ++c) {
        const int r0 = c * Rc;
        const int* lc = lens + r0;

        gather_kernel<<<Mc * 64 / 256, 256, 0, stream>>>(gene, gidx + (size_t)r0 * L_, lc, Xa, flag);

        for (int i = 0; i < 2; ++i) {
            gemm_bt_kernel<<<dim3(Mc / 128, 6), 256, 0, stream>>>(
                Xa, 512, wQKV + (size_t)i * 1536 * 512, cbqkv + i * 1536, QKV, 1536, 0);
            attn_enc_kernel<<<Rc, 256, 0, stream>>>(QKV, lc);
            gemm_ln_kernel<<<Mc / 128, 512, 0, stream>>>(
                QKV, 1536, wO + i * CC, cbo + i * C_, Xa, 512,
                cg1 + i * C_, cb1 + i * C_, Xa, 512, lc, 1, 0);
            gemm_ln_kernel<<<Mc / 128, 512, 0, stream>>>(
                Xa, 512, wF + i * CC, cff + i * C_, Xa, 512,
                cg2 + i * C_, cb2 + i * C_, Xa, 512, lc, 0, 1);
        }

        // pma_lin: Y = relu(Xa @ pmaW^T + b)
        gemm_bt_kernel<<<dim3(Mc / 128, 2), 256, 0, stream>>>(Xa, 512, wP, cpb, Y, 512, 1);
        seed_kernel<<<Rc * 64 / 256, 256, 0, stream>>>(csd, S0);
        // PMA Q-proj (seed): S1 = S0 @ Wq2^T + bq2
        gemm_bt_kernel<<<dim3(Rc / 128, 2), 256, 0, stream>>>(S0, 512, wQ2, cbq + 2 * C_, S1, 512, 0);
        // PMA K,V packed: KVb = Y @ [Wk2;Wv2]^T
        gemm_bt_kernel<<<dim3(Mc / 128, 4), 256, 0, stream>>>(Y, 512, wKV2, cbkv2, KVb, 1024, 0);
        attn_pma_kernel<<<dim3(Rc, H_), 64, 0, stream>>>(S1, KVb, S2, lc);
        gemm_ln_kernel<<<Rc / 128, 512, 0, stream>>>(
            S2, 512, wO + 2 * CC, cbo + 2 * C_, S0, 512,
            cg1 + 2 * C_, cb1 + 2 * C_, S0, 512, lc, 0, 0);
        gemm_ln_kernel<<<Rc / 128, 512, 0, stream>>>(
            S0, 512, wF + 2 * CC, cff + 2 * C_, S0, 512,
            cg2 + 2 * C_, cb2 + 2 * C_, S0, 512, lc, 0, 1);

        // decoder SAB (Lq=Lk=1): attn out == V
        gemm_bt_kernel<<<dim3(Rc / 128, 2), 256, 0, stream>>>(S0, 512, wV3, cbv + 3 * C_, S1, 512, 0);
        gemm_ln_kernel<<<Rc / 128, 512, 0, stream>>>(
            S1, 512, wO + 3 * CC, cbo + 3 * C_, S0, 512,
            cg1 + 3 * C_, cb1 + 3 * C_, S0, 512, lc, 0, 0);
        gemm_ln_kernel<<<Rc / 128, 512, 0, stream>>>(
            S0, 512, wF + 3 * CC, cff + 3 * C_, S0, 512,
            cg2 + 3 * C_, cb2 + 3 * C_, S0, 512, lc, 0, 1);

        final_kernel<<<Rc * 64 / 256, 256, 0, stream>>>(S0, lc, d_out, flag, (size_t)r0 * C_);
    }
}